// Round 1
// baseline (4885.959 us; speedup 1.0000x reference)
//
#include <hip/hip_runtime.h>
#include <hip/hip_fp16.h>

#define BB 8
#define SS 2048
#define EE 1024
#define NHH 4
#define DHH 256

__device__ __forceinline__ __half2 u2h2(unsigned int u) {
  union { unsigned int u; __half2 h; } c; c.u = u; return c.h;
}
__device__ __forceinline__ unsigned int h2u(__half2 h) {
  union { unsigned int u; __half2 h; } c; c.h = h; return c.u;
}

// ---------------------------------------------------------------------------
// Gates projection GEMM, conv+SiLU fused into A-staging for pair 0.
// grid (256 m-tiles, 8 n-tiles, 8 problems), block 256.
// problem p: h = p>>1, pair = p&1. pair0: A = silu(conv(x)), W = [fgate;igate]
//                                  pair1: A = x,             W = [zgate;ogate]
// Output: gx f16, layout [S][B][NH][4*DH]
// ---------------------------------------------------------------------------
__global__ __launch_bounds__(256) void gates_gemm(
    const float* __restrict__ x, const float* __restrict__ conv_w,
    const float* __restrict__ conv_b,
    const float* __restrict__ fgw, const float* __restrict__ igw,
    const float* __restrict__ zgw, const float* __restrict__ ogw,
    __half* __restrict__ gx)
{
  __shared__ float Xs[67][33];
  __shared__ float As[64][33];
  __shared__ float Bs[32][68];

  const int tid = threadIdx.x;
  const int mt = blockIdx.x;           // 0..255
  const int nt = blockIdx.y;           // 0..7
  const int p  = blockIdx.z;           // 0..7
  const int h  = p >> 1, pair = p & 1;
  const int b  = mt >> 5;              // 2048/64 = 32 m-tiles per batch
  const int s0 = (mt & 31) << 6;
  const int n0 = nt << 6;              // 0..448 within [0,512)

  const float* W0 = pair ? zgw : fgw;  // output cols [0,256)
  const float* W1 = pair ? ogw : igw;  // output cols [256,512)

  const int tx = tid & 15, ty = tid >> 4;
  float acc[4][4] = {};

  for (int d0 = 0; d0 < DHH; d0 += 32) {
    // stage X rows s0-3 .. s0+63 for head h, cols d0..d0+31
    for (int i = tid; i < 67 * 32; i += 256) {
      int r = i >> 5, c = i & 31;
      int s = s0 - 3 + r;
      float v = 0.f;
      if (s >= 0) v = x[((size_t)b * SS + s) * EE + h * DHH + d0 + c];
      Xs[r][c] = v;
    }
    // stage B: Bs[c][j] = W[n0+j][d0+c]  (coalesced over c)
    for (int i = tid; i < 32 * 64; i += 256) {
      int j = i >> 5, c = i & 31;
      int o = n0 + j;
      const float* Wp = (o < 256) ? W0 : W1;
      int oo = o & 255;
      Bs[c][j] = Wp[((size_t)h * DHH + oo) * DHH + d0 + c];
    }
    __syncthreads();
    if (pair == 0) {
      for (int i = tid; i < 64 * 32; i += 256) {
        int r = i >> 5, c = i & 31;
        int e = h * DHH + d0 + c;
        float xc = conv_b[e];
        xc = fmaf(Xs[r + 0][c], conv_w[0 * EE + e], xc);
        xc = fmaf(Xs[r + 1][c], conv_w[1 * EE + e], xc);
        xc = fmaf(Xs[r + 2][c], conv_w[2 * EE + e], xc);
        xc = fmaf(Xs[r + 3][c], conv_w[3 * EE + e], xc);
        float sg = 1.f / (1.f + __expf(-xc));
        As[r][c] = xc * sg;
      }
    } else {
      for (int i = tid; i < 64 * 32; i += 256) {
        int r = i >> 5, c = i & 31;
        As[r][c] = Xs[r + 3][c];
      }
    }
    __syncthreads();
#pragma unroll
    for (int kk = 0; kk < 32; ++kk) {
      float a[4];
#pragma unroll
      for (int i = 0; i < 4; ++i) a[i] = As[ty * 4 + i][kk];
      float4 bv = *(const float4*)&Bs[kk][tx * 4];
      float bb[4] = {bv.x, bv.y, bv.z, bv.w};
#pragma unroll
      for (int i = 0; i < 4; ++i)
#pragma unroll
        for (int j = 0; j < 4; ++j)
          acc[i][j] = fmaf(a[i], bb[j], acc[i][j]);
    }
    __syncthreads();
  }

  // write 4x4 f16 results; 4 consecutive halves -> one uint2 store (8B aligned)
#pragma unroll
  for (int i = 0; i < 4; ++i) {
    int s = s0 + ty * 4 + i;
    size_t base = (((size_t)s * BB + b) * NHH + h) * 1024 + (size_t)pair * 512 + n0 + tx * 4;
    uint2 st;
    st.x = h2u(__floats2half2_rn(acc[i][0], acc[i][1]));
    st.y = h2u(__floats2half2_rn(acc[i][2], acc[i][3]));
    *(uint2*)(gx + base) = st;
  }
}

// ---------------------------------------------------------------------------
// sLSTM scan: one workgroup (512 threads) per chain (b,h). Weight-stationary:
// col k0 = t       (gate i/f): 128 half2 in VGPRs
// col k1 = 512 + t (gate z/o): pairs 0..63 in VGPRs, pairs 64..127 in LDS
// y double-buffered in LDS (f16), broadcast-read as uint4.
// Dynamic LDS: 131072 (weights) + 1024 (ypub x2) + 4096 (exchange) = 136192 B
// ---------------------------------------------------------------------------
__global__ __launch_bounds__(512, 2) void slstm_scan(
    const float* __restrict__ rk,    // (NH, DH, 4*DH)
    const float* __restrict__ rb,    // (NH, 4, DH)
    const __half* __restrict__ gx,   // [S][B][NH][1024]
    float* __restrict__ out)         // (B, S, E)
{
  extern __shared__ unsigned char smem[];
  uint2* wl    = (uint2*)smem;                      // [32][512]
  __half* ypub = (__half*)(smem + 131072);          // [2][256]
  float2* exch = (float2*)(smem + 131072 + 1024);   // [512]

  const int t = threadIdx.x;
  const int b = blockIdx.x >> 2, h = blockIdx.x & 3;
  const float* Rh = rk + (size_t)h * DHH * 1024;
  const int k0 = t, k1 = 512 + t;

  __half2 w0[128];
  __half2 w1r[64];
#pragma unroll
  for (int pp = 0; pp < 128; ++pp)
    w0[pp] = __floats2half2_rn(Rh[(2 * pp) * 1024 + k0], Rh[(2 * pp + 1) * 1024 + k0]);
#pragma unroll
  for (int pp = 0; pp < 64; ++pp)
    w1r[pp] = __floats2half2_rn(Rh[(2 * pp) * 1024 + k1], Rh[(2 * pp + 1) * 1024 + k1]);
  for (int q = 0; q < 32; ++q) {
    // uint2 q holds pairs (64+2q, 65+2q) of col k1 = elems 128+4q .. 131+4q
    __half2 pa = __floats2half2_rn(Rh[(128 + 4 * q + 0) * 1024 + k1],
                                   Rh[(128 + 4 * q + 1) * 1024 + k1]);
    __half2 pb = __floats2half2_rn(Rh[(128 + 4 * q + 2) * 1024 + k1],
                                   Rh[(128 + 4 * q + 3) * 1024 + k1]);
    uint2 u; u.x = h2u(pa); u.y = h2u(pb);
    wl[q * 512 + t] = u;
  }
  const float rb0 = rb[h * 1024 + k0];
  const float rb1 = rb[h * 1024 + k1];
  float c = 0.f, n = 0.f, m = 0.f;
  if (t < 256) ypub[t] = __float2half(0.f);
  __syncthreads();

  int cur = 0;
  const size_t gxbase = ((size_t)b * NHH + h) * 1024;
  const __half2 hz = __floats2half2_rn(0.f, 0.f);

  for (int st = 0; st < SS; ++st) {
    const __half xt0 = gx[(size_t)st * (BB * NHH * 1024) + gxbase + k0];
    const __half xt1 = gx[(size_t)st * (BB * NHH * 1024) + gxbase + k1];

    const uint4* yv = (const uint4*)(ypub + cur * 256);
    __half2 s0a = hz, s0b = hz, s1a = hz, s1b = hz;
#pragma unroll
    for (int j = 0; j < 32; ++j) {
      uint4 yq = yv[j];   // y half2 pairs 4j..4j+3 (broadcast read)
      __half2 y0 = u2h2(yq.x), y1 = u2h2(yq.y), y2 = u2h2(yq.z), y3 = u2h2(yq.w);
      if (j < 16) {
        s0a = __hfma2(w0[4 * j + 0], y0, s0a);
        s1a = __hfma2(w1r[4 * j + 0], y0, s1a);
        s0b = __hfma2(w0[4 * j + 1], y1, s0b);
        s1b = __hfma2(w1r[4 * j + 1], y1, s1b);
        s0a = __hfma2(w0[4 * j + 2], y2, s0a);
        s1a = __hfma2(w1r[4 * j + 2], y2, s1a);
        s0b = __hfma2(w0[4 * j + 3], y3, s0b);
        s1b = __hfma2(w1r[4 * j + 3], y3, s1b);
      } else {
        uint2 qa = wl[(2 * (j - 16) + 0) * 512 + t];  // pairs 4j, 4j+1
        uint2 qb = wl[(2 * (j - 16) + 1) * 512 + t];  // pairs 4j+2, 4j+3
        s0a = __hfma2(w0[4 * j + 0], y0, s0a);
        s1a = __hfma2(u2h2(qa.x), y0, s1a);
        s0b = __hfma2(w0[4 * j + 1], y1, s0b);
        s1b = __hfma2(u2h2(qa.y), y1, s1b);
        s0a = __hfma2(w0[4 * j + 2], y2, s0a);
        s1a = __hfma2(u2h2(qb.x), y2, s1a);
        s0b = __hfma2(w0[4 * j + 3], y3, s0b);
        s1b = __hfma2(u2h2(qb.y), y3, s1b);
      }
    }
    float acc0 = __low2float(s0a) + __high2float(s0a) + __low2float(s0b) + __high2float(s0b);
    float acc1 = __low2float(s1a) + __high2float(s1a) + __low2float(s1b) + __high2float(s1b);
    float raw0 = acc0 + __half2float(xt0) + rb0;
    float raw1 = acc1 + __half2float(xt1) + rb1;
    exch[t] = make_float2(raw0, raw1);
    __syncthreads();
    if (t < 256) {
      float2 fo = exch[t + 256];
      float iv = raw0, zv = raw1, fv = fo.x, ov = fo.y;
      float ls = (fv < 0.f ? fv : 0.f) - log1pf(__expf(-fabsf(fv)));
      float lfm = m + ls;
      float mn = fmaxf(iv, lfm);
      float ig = __expf(iv - mn);
      float fg = __expf(lfm - mn);
      c = fg * c + ig * tanhf(zv);
      n = fg * n + ig;
      float og = 1.f / (1.f + __expf(-ov));
      float y = og * c / n;
      m = mn;
      out[((size_t)b * SS + st) * EE + h * DHH + t] = y;
      ypub[(cur ^ 1) * 256 + t] = __float2half(y);
    }
    __syncthreads();
    cur ^= 1;
  }
}

// ---------------------------------------------------------------------------
// GroupNorm over DH per (b,s,h), in place on out. One wave = one head.
// ---------------------------------------------------------------------------
__global__ __launch_bounds__(256) void groupnorm(
    float* __restrict__ y, const float* __restrict__ gnw)
{
  const int row = blockIdx.x;   // b*S + s
  const int t = threadIdx.x;    // 0..255; wave = head
  float4 v = ((const float4*)y)[(size_t)row * 256 + t];
  float s = v.x + v.y + v.z + v.w;
  float q = v.x * v.x + v.y * v.y + v.z * v.z + v.w * v.w;
#pragma unroll
  for (int mask = 1; mask < 64; mask <<= 1) {
    s += __shfl_xor(s, mask, 64);
    q += __shfl_xor(q, mask, 64);
  }
  float mu = s * (1.f / 256.f);
  float var = q * (1.f / 256.f) - mu * mu;
  float rs = rsqrtf(var + 1e-5f);
  float4 g = ((const float4*)gnw)[t];
  float4 o;
  o.x = (v.x - mu) * rs * g.x;
  o.y = (v.y - mu) * rs * g.y;
  o.z = (v.z - mu) * rs * g.z;
  o.w = (v.w - mu) * rs * g.w;
  ((float4*)y)[(size_t)row * 256 + t] = o;
}

extern "C" void kernel_launch(void* const* d_in, const int* in_sizes, int n_in,
                              void* d_out, int out_size, void* d_ws, size_t ws_size,
                              hipStream_t stream) {
  const float* x      = (const float*)d_in[0];
  const float* conv_w = (const float*)d_in[1];
  const float* conv_b = (const float*)d_in[2];
  const float* fgw    = (const float*)d_in[3];
  const float* igw    = (const float*)d_in[4];
  const float* zgw    = (const float*)d_in[5];
  const float* ogw    = (const float*)d_in[6];
  const float* rk     = (const float*)d_in[7];
  const float* rb     = (const float*)d_in[8];
  const float* gnw    = (const float*)d_in[9];
  float* out = (float*)d_out;
  __half* gx = (__half*)d_ws;   // [S][B][NH][1024] f16 = 134217728 B

  dim3 g1(256, 8, 8);
  gates_gemm<<<g1, 256, 0, stream>>>(x, conv_w, conv_b, fgw, igw, zgw, ogw, gx);

  const int scan_lds = 131072 + 1024 + 4096;
  hipFuncSetAttribute(reinterpret_cast<const void*>(slstm_scan),
                      hipFuncAttributeMaxDynamicSharedMemorySize, scan_lds);
  slstm_scan<<<32, 512, scan_lds, stream>>>(rk, rb, gx, out);

  groupnorm<<<BB * SS, 256, 0, stream>>>(out, gnw);
}

// Round 3
// 4577.752 us; speedup vs baseline: 1.0673x; 1.0673x over previous
//
#include <hip/hip_runtime.h>
#include <hip/hip_fp16.h>

#define BB 8
#define SS 2048
#define EE 1024
#define NHH 4
#define DHH 256

__device__ __forceinline__ __half2 u2h2(unsigned int u) {
  union { unsigned int u; __half2 h; } c; c.u = u; return c.h;
}
__device__ __forceinline__ unsigned int h2u(__half2 h) {
  union { unsigned int u; __half2 h; } c; c.h = h; return c.u;
}

// ---------------------------------------------------------------------------
// Gates projection GEMM, conv+SiLU fused into A-staging for pair 0.
// grid (256 m-tiles, 8 n-tiles, 8 problems), block 256.
// problem p: h = p>>1, pair = p&1. pair0: A = silu(conv(x)), W = [fgate;igate]
//                                  pair1: A = x,             W = [zgate;ogate]
// Output: gx f16, layout [S][B][NH][4*DH] = [i(256) f(256) z(256) o(256)]
// ---------------------------------------------------------------------------
__global__ __launch_bounds__(256) void gates_gemm(
    const float* __restrict__ x, const float* __restrict__ conv_w,
    const float* __restrict__ conv_b,
    const float* __restrict__ fgw, const float* __restrict__ igw,
    const float* __restrict__ zgw, const float* __restrict__ ogw,
    __half* __restrict__ gx)
{
  __shared__ float Xs[67][33];
  __shared__ float As[64][33];
  __shared__ float Bs[32][68];

  const int tid = threadIdx.x;
  const int mt = blockIdx.x;           // 0..255
  const int nt = blockIdx.y;           // 0..7
  const int p  = blockIdx.z;           // 0..7
  const int h  = p >> 1, pair = p & 1;
  const int b  = mt >> 5;              // 2048/64 = 32 m-tiles per batch
  const int s0 = (mt & 31) << 6;
  const int n0 = nt << 6;              // 0..448 within [0,512)

  const float* W0 = pair ? zgw : fgw;  // output cols [0,256)
  const float* W1 = pair ? ogw : igw;  // output cols [256,512)

  const int tx = tid & 15, ty = tid >> 4;
  float acc[4][4] = {};

  for (int d0 = 0; d0 < DHH; d0 += 32) {
    for (int i = tid; i < 67 * 32; i += 256) {
      int r = i >> 5, c = i & 31;
      int s = s0 - 3 + r;
      float v = 0.f;
      if (s >= 0) v = x[((size_t)b * SS + s) * EE + h * DHH + d0 + c];
      Xs[r][c] = v;
    }
    for (int i = tid; i < 32 * 64; i += 256) {
      int j = i >> 5, c = i & 31;
      int o = n0 + j;
      const float* Wp = (o < 256) ? W0 : W1;
      int oo = o & 255;
      Bs[c][j] = Wp[((size_t)h * DHH + oo) * DHH + d0 + c];
    }
    __syncthreads();
    if (pair == 0) {
      for (int i = tid; i < 64 * 32; i += 256) {
        int r = i >> 5, c = i & 31;
        int e = h * DHH + d0 + c;
        float xc = conv_b[e];
        xc = fmaf(Xs[r + 0][c], conv_w[0 * EE + e], xc);
        xc = fmaf(Xs[r + 1][c], conv_w[1 * EE + e], xc);
        xc = fmaf(Xs[r + 2][c], conv_w[2 * EE + e], xc);
        xc = fmaf(Xs[r + 3][c], conv_w[3 * EE + e], xc);
        float sg = 1.f / (1.f + __expf(-xc));
        As[r][c] = xc * sg;
      }
    } else {
      for (int i = tid; i < 64 * 32; i += 256) {
        int r = i >> 5, c = i & 31;
        As[r][c] = Xs[r + 3][c];
      }
    }
    __syncthreads();
#pragma unroll
    for (int kk = 0; kk < 32; ++kk) {
      float a[4];
#pragma unroll
      for (int i = 0; i < 4; ++i) a[i] = As[ty * 4 + i][kk];
      float4 bv = *(const float4*)&Bs[kk][tx * 4];
      float bb[4] = {bv.x, bv.y, bv.z, bv.w};
#pragma unroll
      for (int i = 0; i < 4; ++i)
#pragma unroll
        for (int j = 0; j < 4; ++j)
          acc[i][j] = fmaf(a[i], bb[j], acc[i][j]);
    }
    __syncthreads();
  }

#pragma unroll
  for (int i = 0; i < 4; ++i) {
    int s = s0 + ty * 4 + i;
    size_t base = (((size_t)s * BB + b) * NHH + h) * 1024 + (size_t)pair * 512 + n0 + tx * 4;
    uint2 st;
    st.x = h2u(__floats2half2_rn(acc[i][0], acc[i][1]));
    st.y = h2u(__floats2half2_rn(acc[i][2], acc[i][3]));
    *(uint2*)(gx + base) = st;
  }
}

// ---------------------------------------------------------------------------
// sLSTM scan: one workgroup (512 threads) per chain (b,h).
// Lane-pair layout: thread pair (2d, 2d+1) owns dim d.
//   even lane: cols k0=d (gate i), k1=512+d (gate z)
//   odd  lane: cols k0=256+d (gate f), k1=768+d (gate o)
// Weights: col k0 fully in VGPR (128 half2); col k1: 64 half2 VGPR + 64
// half2-pairs in LDS. y double-buffered in LDS (f16), broadcast uint4 reads.
// One barrier per step; gate exchange via in-wave __shfl_xor(.,1).
// Dynamic LDS: 131072 (weights) + 1024 (ypub x2) = 132096 B
// ---------------------------------------------------------------------------
__global__ __launch_bounds__(512) void slstm_scan(
    const float* __restrict__ rk,    // (NH, DH, 4*DH)
    const float* __restrict__ rb,    // (NH, 4, DH)
    const __half* __restrict__ gx,   // [S][B][NH][1024]
    float* __restrict__ out)         // (B, S, E)
{
  extern __shared__ unsigned char smem[];
  uint2* wl    = (uint2*)smem;                      // [32][512]
  __half* ypub = (__half*)(smem + 131072);          // [2][256]

  const int t = threadIdx.x;
  const int b = blockIdx.x >> 2, h = blockIdx.x & 3;
  const int d = t >> 1, par = t & 1;
  const int k0 = par * 256 + d;
  const int k1 = 512 + par * 256 + d;
  const float* Rh = rk + (size_t)h * DHH * 1024;

  __half2 w0[128];
  __half2 w1r[64];
#pragma unroll
  for (int pp = 0; pp < 128; ++pp)
    w0[pp] = __floats2half2_rn(Rh[(2 * pp) * 1024 + k0], Rh[(2 * pp + 1) * 1024 + k0]);
#pragma unroll
  for (int pp = 0; pp < 64; ++pp)
    w1r[pp] = __floats2half2_rn(Rh[(2 * pp) * 1024 + k1], Rh[(2 * pp + 1) * 1024 + k1]);
  for (int q = 0; q < 32; ++q) {
    // uint2 q holds half2-pairs (64+2q, 65+2q) of col k1 = elems 128+4q..131+4q
    __half2 pa = __floats2half2_rn(Rh[(128 + 4 * q + 0) * 1024 + k1],
                                   Rh[(128 + 4 * q + 1) * 1024 + k1]);
    __half2 pb = __floats2half2_rn(Rh[(128 + 4 * q + 2) * 1024 + k1],
                                   Rh[(128 + 4 * q + 3) * 1024 + k1]);
    uint2 u; u.x = h2u(pa); u.y = h2u(pb);
    wl[q * 512 + t] = u;
  }
  const float rb0 = rb[h * 1024 + k0];
  const float rb1 = rb[h * 1024 + k1];
  float c = 0.f, n = 0.f, m = 0.f;
  if (t < 256) ypub[t] = __float2half(0.f);
  __syncthreads();

  int cur = 0;
  const __half* pg = gx + ((size_t)b * NHH + h) * 1024;
  float cx0 = __half2float(pg[k0]);
  float cx1 = __half2float(pg[k1]);
  const __half2 hz = __floats2half2_rn(0.f, 0.f);
  const size_t out_base = ((size_t)b * SS) * EE + h * DHH + d;

  for (int st = 0; st < SS; ++st) {
    // prefetch next step's gate inputs (consumed at end of this iteration)
    const __half* pn = pg + ((st + 1 < SS) ? (size_t)(BB * NHH * 1024) : 0);
    const __half nx0 = pn[k0];
    const __half nx1 = pn[k1];

    const uint4* yv = (const uint4*)(ypub + cur * 256);
    __half2 s0a = hz, s0b = hz, s1a = hz, s1b = hz;
#pragma unroll
    for (int j = 0; j < 32; ++j) {
      uint4 yq = yv[j];   // y half2 pairs 4j..4j+3 (broadcast read)
      __half2 y0 = u2h2(yq.x), y1 = u2h2(yq.y), y2 = u2h2(yq.z), y3 = u2h2(yq.w);
      if (j < 16) {
        s0a = __hfma2(w0[4 * j + 0], y0, s0a);
        s1a = __hfma2(w1r[4 * j + 0], y0, s1a);
        s0b = __hfma2(w0[4 * j + 1], y1, s0b);
        s1b = __hfma2(w1r[4 * j + 1], y1, s1b);
        s0a = __hfma2(w0[4 * j + 2], y2, s0a);
        s1a = __hfma2(w1r[4 * j + 2], y2, s1a);
        s0b = __hfma2(w0[4 * j + 3], y3, s0b);
        s1b = __hfma2(w1r[4 * j + 3], y3, s1b);
      } else {
        uint2 qa = wl[(2 * (j - 16) + 0) * 512 + t];  // pairs 4j, 4j+1
        uint2 qb = wl[(2 * (j - 16) + 1) * 512 + t];  // pairs 4j+2, 4j+3
        s0a = __hfma2(w0[4 * j + 0], y0, s0a);
        s1a = __hfma2(u2h2(qa.x), y0, s1a);
        s0b = __hfma2(w0[4 * j + 1], y1, s0b);
        s1b = __hfma2(u2h2(qa.y), y1, s1b);
        s0a = __hfma2(w0[4 * j + 2], y2, s0a);
        s1a = __hfma2(u2h2(qb.x), y2, s1a);
        s0b = __hfma2(w0[4 * j + 3], y3, s0b);
        s1b = __hfma2(u2h2(qb.y), y3, s1b);
      }
    }
    float acc0 = __low2float(s0a) + __high2float(s0a) + __low2float(s0b) + __high2float(s0b);
    float acc1 = __low2float(s1a) + __high2float(s1a) + __low2float(s1b) + __high2float(s1b);
    float raw0 = acc0 + cx0 + rb0;
    float raw1 = acc1 + cx1 + rb1;

    // in-wave exchange with partner lane (even<->odd): no LDS, no barrier
    float pr0 = __shfl_xor(raw0, 1);
    float pr1 = __shfl_xor(raw1, 1);
    float iv = par ? pr0 : raw0;
    float fv = par ? raw0 : pr0;
    float zv = par ? pr1 : raw1;
    float ov = par ? raw1 : pr1;

    // state update (computed redundantly by both lanes of the pair)
    float ea = __expf(-fabsf(fv));
    float ls = fminf(fv, 0.f) - __logf(1.f + ea);      // log_sigmoid(fv)
    float lfm = m + ls;
    float mn = fmaxf(iv, lfm);
    float ig = __expf(iv - mn);
    float fg = __expf(lfm - mn);
    float pz = __expf(-2.f * fabsf(zv));
    float tmag = __fdividef(1.f - pz, 1.f + pz);
    float th = (zv < 0.f) ? -tmag : tmag;              // tanh(zv)
    c = fg * c + ig * th;
    n = fg * n + ig;
    float og = __fdividef(1.f, 1.f + __expf(-ov));     // sigmoid(ov)
    float y = og * __fdividef(c, n);
    m = mn;

    if (par == 0) {
      out[out_base + (size_t)st * EE] = y;
      ypub[(cur ^ 1) * 256 + d] = __float2half(y);
    }
    __syncthreads();
    cur ^= 1;
    pg = pn;
    cx0 = __half2float(nx0);
    cx1 = __half2float(nx1);
  }
}

// ---------------------------------------------------------------------------
// GroupNorm over DH per (b,s,h), in place on out. One wave = one head.
// ---------------------------------------------------------------------------
__global__ __launch_bounds__(256) void groupnorm(
    float* __restrict__ y, const float* __restrict__ gnw)
{
  const int row = blockIdx.x;   // b*S + s
  const int t = threadIdx.x;    // 0..255; wave = head
  float4 v = ((const float4*)y)[(size_t)row * 256 + t];
  float s = v.x + v.y + v.z + v.w;
  float q = v.x * v.x + v.y * v.y + v.z * v.z + v.w * v.w;
#pragma unroll
  for (int mask = 1; mask < 64; mask <<= 1) {
    s += __shfl_xor(s, mask, 64);
    q += __shfl_xor(q, mask, 64);
  }
  float mu = s * (1.f / 256.f);
  float var = q * (1.f / 256.f) - mu * mu;
  float rs = rsqrtf(var + 1e-5f);
  float4 g = ((const float4*)gnw)[t];
  float4 o;
  o.x = (v.x - mu) * rs * g.x;
  o.y = (v.y - mu) * rs * g.y;
  o.z = (v.z - mu) * rs * g.z;
  o.w = (v.w - mu) * rs * g.w;
  ((float4*)y)[(size_t)row * 256 + t] = o;
}

extern "C" void kernel_launch(void* const* d_in, const int* in_sizes, int n_in,
                              void* d_out, int out_size, void* d_ws, size_t ws_size,
                              hipStream_t stream) {
  const float* x      = (const float*)d_in[0];
  const float* conv_w = (const float*)d_in[1];
  const float* conv_b = (const float*)d_in[2];
  const float* fgw    = (const float*)d_in[3];
  const float* igw    = (const float*)d_in[4];
  const float* zgw    = (const float*)d_in[5];
  const float* ogw    = (const float*)d_in[6];
  const float* rk     = (const float*)d_in[7];
  const float* rb     = (const float*)d_in[8];
  const float* gnw    = (const float*)d_in[9];
  float* out = (float*)d_out;
  __half* gx = (__half*)d_ws;   // [S][B][NH][1024] f16 = 134217728 B

  dim3 g1(256, 8, 8);
  gates_gemm<<<g1, 256, 0, stream>>>(x, conv_w, conv_b, fgw, igw, zgw, ogw, gx);

  const int scan_lds = 131072 + 1024;
  (void)hipFuncSetAttribute(reinterpret_cast<const void*>(slstm_scan),
                            hipFuncAttributeMaxDynamicSharedMemorySize, scan_lds);
  slstm_scan<<<32, 512, scan_lds, stream>>>(rk, rb, gx, out);

  groupnorm<<<BB * SS, 256, 0, stream>>>(out, gnw);
}